// Round 16
// baseline (698.696 us; speedup 1.0000x reference)
//
#include <hip/hip_runtime.h>
#include <hip/hip_bf16.h>

// Problem constants (from reference)
#define N_NODES 50000
#define N_EDGES 200000
#define BGRAPHS 512
#define F0c 78
#define H1c 10
#define HC1 780     // H1*F0 (logical)
#define HSTR 800    // padded row stride: 10 head blocks of 80 (78 data + 2 pad)
#define C2c 128
#define SEQc 1000
#define VOCABc 26
#define NFc 32
#define KWc 8
#define LOUTc 121
#define EMBc 128
#define KX 96       // padded cols for xpad (78 -> 96)
#define KXT 3872    // NF*LOUT = 32*121 -> 121 MFMA k-steps, split 11 x 11

typedef __attribute__((ext_vector_type(8))) short short8;
typedef __attribute__((ext_vector_type(4))) float f32x4;
typedef unsigned short u16;

static constexpr size_t alignup(size_t x) { return (x + 255) & ~size_t(255); }

// -------- workspace layout (bytes) --------
// A_HBUF region holds xagg bf16 [N][10][80] = 80,000,000 B.
static constexpr size_t A_HBUF = 0;
static constexpr size_t A_OUT1 = alignup(A_HBUF + size_t(N_NODES)*HSTR*2);   // bf16 [N,800] = 80 MB
static constexpr size_t A_H2   = alignup(A_OUT1 + size_t(N_NODES)*HSTR*2);   // f32  [N,128]
static constexpr size_t A_W2T  = alignup(A_H2   + size_t(N_NODES)*C2c*4);    // bf16 [128,800] padded-80 layout
static constexpr size_t A_ALS1 = alignup(A_W2T  + size_t(C2c)*HSTR*2);
static constexpr size_t A_ALD1 = alignup(A_ALS1 + size_t(N_NODES)*H1c*4);
static constexpr size_t A_ALS2 = alignup(A_ALD1 + size_t(N_NODES)*H1c*4);
static constexpr size_t A_ALD2 = alignup(A_ALS2 + size_t(N_NODES)*4);
static constexpr size_t A_DEG  = alignup(A_ALD2 + size_t(N_NODES)*4);
static constexpr size_t A_OFFS = alignup(A_DEG  + size_t(N_NODES)*4);
static constexpr size_t A_CUR  = alignup(A_OFFS + size_t(N_NODES+1)*4);
static constexpr size_t A_CSRC = alignup(A_CUR  + size_t(N_NODES)*4);
static constexpr size_t A_XC   = alignup(A_CSRC + size_t(N_EDGES+N_NODES)*4);
static constexpr size_t A_Y1   = alignup(A_XC   + size_t(BGRAPHS)*256*4);
static constexpr size_t A_BOFF = alignup(A_Y1   + size_t(BGRAPHS)*1024*4);
static constexpr size_t A_BPAD = alignup(A_BOFF + size_t(BGRAPHS)*(VOCABc+1)*4);
static constexpr size_t A_WXT  = alignup(A_BPAD + size_t(HSTR)*4);           // bf16 [128][3872]
static constexpr size_t A_FXP  = alignup(A_WXT  + size_t(C2c)*KXT*2);        // f32 [11][512][128]
static constexpr size_t A_W1HP = alignup(A_FXP  + size_t(11)*BGRAPHS*C2c*4); // bf16 [10][80][96]
static constexpr size_t A_WSD  = alignup(A_W1HP + size_t(10)*80*96*2);       // f32 [2][10][78]
static constexpr size_t A_END  = alignup(A_WSD  + size_t(2)*H1c*F0c*4);

// aliases inside xagg region (valid after k_gemm1h retires; xagg dead then):
static constexpr size_t A_HFIN = A_HBUF;                                        // f32 [N,128]
static constexpr size_t A_AMAT = alignup(A_HFIN + size_t(N_NODES)*C2c*4);
static constexpr size_t A_CVO  = alignup(A_AMAT + size_t(BGRAPHS)*NFc*VOCABc*KWc*4);  // bf16 [512][3872]
static_assert(A_CVO + size_t(BGRAPHS)*KXT*2 <= size_t(N_NODES)*HSTR*2, "alias A overflow");
// alias inside out1 region (xpad dead before gemm1h writes out1):
static constexpr size_t A_XPAD = A_OUT1;                                        // bf16 [N,96]
static_assert(size_t(N_NODES)*KX*2 <= size_t(N_NODES)*HSTR*2, "alias B overflow");

// -------- helpers --------
__device__ __forceinline__ float bflo(unsigned u) { return __uint_as_float(u << 16); }
__device__ __forceinline__ float bfhi(unsigned u) { return __uint_as_float(u & 0xffff0000u); }
__device__ __forceinline__ u16 f2bf(float v) {
    __hip_bfloat16 b = __float2bfloat16(v);
    return *(u16*)&b;
}

// ---------------- prep: deg init + conversions + folded attention vectors ----------------
__global__ void k_prep(const float* __restrict__ x, const float* __restrict__ W1,
                       const float* __restrict__ W2, const float* __restrict__ b1,
                       const float* __restrict__ fcxt_w,
                       const float* __restrict__ a_src1, const float* __restrict__ a_dst1,
                       __hip_bfloat16* __restrict__ xpad, __hip_bfloat16* __restrict__ w1hp,
                       __hip_bfloat16* __restrict__ w2t, float* __restrict__ bpad,
                       __hip_bfloat16* __restrict__ wxt, float* __restrict__ wsd,
                       int* __restrict__ deg) {
    int i = blockIdx.x*256 + threadIdx.x;
    const int R0 = N_NODES;
    const int R1 = R0 + N_NODES*KX;
    const int R2 = R1 + 10*80*96;
    const int R3 = R2 + C2c*HSTR;
    const int R4 = R3 + HSTR;
    const int R5 = R4 + C2c*KXT;
    const int R6 = R5 + 2*H1c*F0c;
    if (i < R0) {
        deg[i] = 1;   // self loop
    } else if (i < R1) {
        int t = i - R0; int n = t / KX, c = t - n*KX;
        xpad[t] = __float2bfloat16(c < F0c ? x[(size_t)n*F0c + c] : 0.f);
    } else if (i < R2) {
        int t = i - R1; int hh = t / 7680, rem = t - hh*7680;
        int j = rem / 96, k = rem - j*96;
        w1hp[t] = __float2bfloat16((j < F0c && k < F0c) ? W1[(size_t)k*HC1 + hh*F0c + j] : 0.f);
    } else if (i < R3) {
        int t = i - R2; int c = t / HSTR, p = t - c*HSTR;
        int hh = p / 80, cc = p - hh*80;
        w2t[t] = __float2bfloat16(cc < F0c ? W2[(size_t)(hh*F0c + cc)*C2c + c] : 0.f);
    } else if (i < R4) {
        int p = i - R3; int hh = p / 80, cc = p - hh*80;
        bpad[p] = (cc < F0c) ? b1[hh*F0c + cc] : 0.f;
    } else if (i < R5) {
        int t = i - R4; int c = t / KXT, j = t - c*KXT;
        wxt[t] = __float2bfloat16(fcxt_w[(size_t)j*C2c + c]);
    } else if (i < R6) {
        int t = i - R5; int sd = t / (H1c*F0c), rem = t - sd*(H1c*F0c);
        int hh = rem / F0c, c = rem - hh*F0c;
        const float* a = sd ? a_dst1 : a_src1;
        float v = 0.f;
        for (int j = 0; j < F0c; j++) v += W1[(size_t)c*HC1 + hh*F0c + j] * a[hh*F0c + j];
        wsd[t] = v;
    }
}
#define PREP_TOTAL (N_NODES + N_NODES*KX + 10*80*96 + C2c*HSTR + HSTR + C2c*KXT + 2*H1c*F0c)

// ---------------- CSR build ----------------
__global__ void k_count(const int* __restrict__ ei, int* deg) {
    int i = blockIdx.x*256 + threadIdx.x;
    if (i < N_EDGES) atomicAdd(&deg[ei[N_EDGES + i]], 1);
}
__global__ void k_scan(const int* __restrict__ deg, int* __restrict__ off,
                       int* __restrict__ cur, int n) {
    __shared__ int wsum[16];
    __shared__ int s_carry;
    int tid = threadIdx.x, lane = tid & 63, wid = tid >> 6;
    if (tid == 0) s_carry = 0;
    __syncthreads();
    for (int base = 0; base < n; base += 1024) {
        int i = base + tid;
        int v0 = (i < n) ? deg[i] : 0;
        int v = v0;
        for (int d = 1; d < 64; d <<= 1) { int t = __shfl_up(v, d, 64); if (lane >= d) v += t; }
        if (lane == 63) wsum[wid] = v;
        __syncthreads();
        if (wid == 0) {
            int w = (lane < 16) ? wsum[lane] : 0;
            for (int d = 1; d < 16; d <<= 1) { int t = __shfl_up(w, d, 64); if (lane >= d) w += t; }
            if (lane < 16) wsum[lane] = w;
        }
        __syncthreads();
        int wprev = (wid > 0) ? wsum[wid-1] : 0;
        int carry = s_carry;
        if (i < n) { int o = carry + wprev + (v - v0); off[i] = o; cur[i] = o; }
        __syncthreads();
        if (tid == 0) s_carry = carry + wsum[15];
        __syncthreads();
    }
    if (tid == 0) off[n] = s_carry;
}
__global__ void k_fill(const int* __restrict__ ei, int* cur, int* __restrict__ csrc) {
    int i = blockIdx.x*256 + threadIdx.x;
    if (i < N_EDGES) {
        int s = ei[i], d = ei[N_EDGES + i];
        int p = atomicAdd(&cur[d], 1);
        csrc[p] = s;
    } else if (i < N_EDGES + N_NODES) {
        int n = i - N_EDGES;
        int p = atomicAdd(&cur[n], 1);
        csrc[p] = n;
    }
}
// determinize: sort each CSR segment (atomic fill order varies run-to-run)
__global__ void k_sortcsr(const int* __restrict__ offs, int* __restrict__ csrc) {
    int n = blockIdx.x*256 + threadIdx.x;
    if (n >= N_NODES) return;
    int s = offs[n], e = offs[n+1];
    for (int i = s + 1; i < e; i++) {
        int v = csrc[i];
        int j = i - 1;
        while (j >= s && csrc[j] > v) { csrc[j+1] = csrc[j]; j--; }
        csrc[j+1] = v;
    }
}

// ---------------- layer-1 attention logits, direct from x: als = x @ (W1_h a_h) ----------------
__global__ void k_att1x(const float* __restrict__ x, const float* __restrict__ wsd,
                        float* __restrict__ als, float* __restrict__ ald) {
    int i = blockIdx.x*256 + threadIdx.x;
    if (i >= N_NODES*H1c) return;
    int n = i / H1c, hh = i - n*H1c;
    const float* xr = x + (size_t)n*F0c;
    const float* ws = wsd + hh*F0c;
    const float* wd = wsd + H1c*F0c + hh*F0c;
    float s1 = 0.f, s2 = 0.f;
    for (int c = 0; c < F0c; c++) { float v = xr[c]; s1 += v*ws[c]; s2 += v*wd[c]; }
    als[i] = s1; ald[i] = s2;
}

// ---------------- layer-1 aggregation in x-space: xagg[n,hh,80] = sum alpha * x[src] ----------------
__global__ void k_agg1x(const unsigned* __restrict__ xpu, const float* __restrict__ als,
                        const float* __restrict__ ald, const int* __restrict__ offs,
                        const int* __restrict__ csrc, unsigned* __restrict__ xaggu) {
    constexpr int H = H1c;
    int dn = blockIdx.x, lane = threadIdx.x;   // 64
    int s = offs[dn], e = offs[dn+1], deg = e - s;
    __shared__ float wexp[64*H];               // 2560 B
    __shared__ int   ssrc[64];
    __shared__ float ms[H], dinv_s[H];

    if (deg <= 64) {
        if (lane < deg) ssrc[lane] = csrc[s + lane];
        __syncthreads();
        for (int idx = lane; idx < deg*H; idx += 64) {
            int j = idx / H, hh = idx - j*H;
            float al = als[(size_t)ssrc[j]*H + hh] + ald[(size_t)dn*H + hh];
            wexp[idx] = (al >= 0.f) ? al : 0.2f*al;
        }
        __syncthreads();
        if (lane < H) {
            float m = -1e30f;
            for (int j = 0; j < deg; j++) m = fmaxf(m, wexp[j*H + lane]);
            float den = 0.f;
            for (int j = 0; j < deg; j++) den += __expf(wexp[j*H + lane] - m);
            ms[lane] = m; dinv_s[lane] = 1.f/(den + 1e-16f);
        }
        __syncthreads();
        for (int idx = lane; idx < deg*H; idx += 64) {
            int hh = idx % H;
            wexp[idx] = __expf(wexp[idx] - ms[hh]) * dinv_s[hh];
        }
        __syncthreads();
        if (lane < 40) {                       // uint c covers x cols 2c,2c+1 (cols 0..79)
            float accL[H], accH[H];
            #pragma unroll
            for (int hh = 0; hh < H; hh++) { accL[hh] = 0.f; accH[hh] = 0.f; }
            int j = 0;
            for (; j + 1 < deg; j += 2) {
                unsigned ua = xpu[(size_t)ssrc[j]*48 + lane];
                unsigned ub = xpu[(size_t)ssrc[j+1]*48 + lane];
                float a0 = bflo(ua), a1 = bfhi(ua), b0 = bflo(ub), b1 = bfhi(ub);
                #pragma unroll
                for (int hh = 0; hh < H; hh++) {
                    float wA = wexp[j*H + hh], wB = wexp[(j+1)*H + hh];
                    accL[hh] += wA*a0 + wB*b0;
                    accH[hh] += wA*a1 + wB*b1;
                }
            }
            if (j < deg) {
                unsigned ua = xpu[(size_t)ssrc[j]*48 + lane];
                float a0 = bflo(ua), a1 = bfhi(ua);
                #pragma unroll
                for (int hh = 0; hh < H; hh++) {
                    float wA = wexp[j*H + hh];
                    accL[hh] += wA*a0;
                    accH[hh] += wA*a1;
                }
            }
            #pragma unroll
            for (int hh = 0; hh < H; hh++) {
                unsigned p = (unsigned)f2bf(accL[hh]) | ((unsigned)f2bf(accH[hh]) << 16);
                xaggu[((size_t)dn*H + hh)*40 + lane] = p;
            }
        }
    } else {
        // fallback deg>64 (practically never): recompute alpha inline, guaranteed correct
        if (lane < H) {
            float adv = ald[(size_t)dn*H + lane];
            float m = -1e30f;
            for (int j = s; j < e; j++) {
                float al = als[(size_t)csrc[j]*H + lane] + adv;
                al = (al >= 0.f) ? al : 0.2f*al;
                m = fmaxf(m, al);
            }
            float den = 0.f;
            for (int j = s; j < e; j++) {
                float al = als[(size_t)csrc[j]*H + lane] + adv;
                al = (al >= 0.f) ? al : 0.2f*al;
                den += __expf(al - m);
            }
            ms[lane] = m; dinv_s[lane] = 1.f/(den + 1e-16f);
        }
        __syncthreads();
        if (lane < 40) {
            float accL[H], accH[H];
            #pragma unroll
            for (int hh = 0; hh < H; hh++) { accL[hh] = 0.f; accH[hh] = 0.f; }
            for (int j = s; j < e; j++) {
                int sj = csrc[j];
                unsigned ua = xpu[(size_t)sj*48 + lane];
                float a0 = bflo(ua), a1 = bfhi(ua);
                #pragma unroll
                for (int hh = 0; hh < H; hh++) {
                    float al = als[(size_t)sj*H + hh] + ald[(size_t)dn*H + hh];
                    al = (al >= 0.f) ? al : 0.2f*al;
                    float a = __expf(al - ms[hh]) * dinv_s[hh];
                    accL[hh] += a*a0;
                    accH[hh] += a*a1;
                }
            }
            #pragma unroll
            for (int hh = 0; hh < H; hh++) {
                unsigned p = (unsigned)f2bf(accL[hh]) | ((unsigned)f2bf(accH[hh]) << 16);
                xaggu[((size_t)dn*H + hh)*40 + lane] = p;
            }
        }
    }
}

// ---------------- per-head GEMM: xagg[n,hh,80] @ W1_hh[80x80] -> out1 (elu+bias fused) ----------------
__global__ void k_gemm1h(const short* __restrict__ xagg, const short* __restrict__ w1hp,
                         const float* __restrict__ bpad, u16* __restrict__ out1) {
    int wave = threadIdx.x >> 6, lane = threadIdx.x & 63;
    int m16 = lane & 15, quad = lane >> 4;
    int hh = blockIdx.y;
    int r0 = blockIdx.x*64 + wave*16;
    int rowc = min(r0 + m16, N_NODES-1);
    const short8* arow = (const short8*)(xagg + ((size_t)rowc*H1c + hh)*80);
    f32x4 acc[5];
    #pragma unroll
    for (int ct = 0; ct < 5; ct++) acc[ct] = (f32x4){0.f,0.f,0.f,0.f};
    #pragma unroll
    for (int kt = 0; kt < 3; kt++) {
        short8 af = arow[kt*4 + quad];    // kt=2,quad>=2 overreads: B zeros neutralize
        #pragma unroll
        for (int ct = 0; ct < 5; ct++) {
            const short8* brow = (const short8*)(w1hp + (size_t)(hh*80 + ct*16 + m16)*96);
            short8 bf = brow[kt*4 + quad];
            acc[ct] = __builtin_amdgcn_mfma_f32_16x16x32_bf16(af, bf, acc[ct], 0, 0, 0);
        }
    }
    #pragma unroll
    for (int ct = 0; ct < 5; ct++) {
        int col = ct*16 + m16;
        float bv = bpad[hh*80 + col];
        #pragma unroll
        for (int r = 0; r < 4; r++) {
            int orow = r0 + quad*4 + r;
            if (orow < N_NODES) {
                float v = acc[ct][r] + bv;
                v = (v > 0.f) ? v : (__expf(v) - 1.f);
                out1[(size_t)orow*HSTR + hh*80 + col] = f2bf(v);
            }
        }
    }
}

// ---------------- GEMM2 (MFMA) + att2 fold: out1 @ W2t^T -> h2, als2, ald2 ----------------
__global__ void k_gemm2_mfma(const short* __restrict__ A, const short* __restrict__ Bt,
                             const float* __restrict__ a_src2, const float* __restrict__ a_dst2,
                             float* __restrict__ Cout, float* __restrict__ als2,
                             float* __restrict__ ald2) {
    int wave = threadIdx.x >> 6, lane = threadIdx.x & 63;
    int m16 = lane & 15, quad = lane >> 4;
    int r0 = blockIdx.x*64 + wave*16;
    int rowc = min(r0 + m16, N_NODES-1);
    const short8* arow = (const short8*)(A + (size_t)rowc*HSTR);
    f32x4 acc[8];
    #pragma unroll
    for (int ct = 0; ct < 8; ct++) acc[ct] = (f32x4){0.f,0.f,0.f,0.f};
    for (int kt = 0; kt < 25; kt++) {
        short8 af = arow[kt*4 + quad];
        #pragma unroll
        for (int ct = 0; ct < 8; ct++) {
            const short8* brow = (const short8*)(Bt + (size_t)(ct*16 + m16)*HSTR);
            short8 bf = brow[kt*4 + quad];
            acc[ct] = __builtin_amdgcn_mfma_f32_16x16x32_bf16(af, bf, acc[ct], 0, 0, 0);
        }
    }
    #pragma unroll
    for (int ct = 0; ct < 8; ct++) {
        #pragma unroll
        for (int r = 0; r < 4; r++) {
            int orow = r0 + quad*4 + r;
            if (orow < N_NODES) Cout[(size_t)orow*C2c + ct*16 + m16] = acc[ct][r];
        }
    }
    float asv[8], adv[8];
    #pragma unroll
    for (int ct = 0; ct < 8; ct++) { asv[ct] = a_src2[ct*16 + m16]; adv[ct] = a_dst2[ct*16 + m16]; }
    #pragma unroll
    for (int r = 0; r < 4; r++) {
        float s1 = 0.f, s2 = 0.f;
        #pragma unroll
        for (int ct = 0; ct < 8; ct++) { s1 += acc[ct][r]*asv[ct]; s2 += acc[ct][r]*adv[ct]; }
        #pragma unroll
        for (int d = 1; d < 16; d <<= 1) { s1 += __shfl_xor(s1, d, 64); s2 += __shfl_xor(s2, d, 64); }
        int orow = r0 + quad*4 + r;
        if (m16 == 0 && orow < N_NODES) { als2[orow] = s1; ald2[orow] = s2; }
    }
}

// ---------------- GAT layer-2 aggregation (H=1, C=128 f32) ----------------
__global__ void k_agg2(const float* __restrict__ h2, const float* __restrict__ als,
                       const float* __restrict__ ald, const int* __restrict__ offs,
                       const int* __restrict__ csrc, const float* __restrict__ b2,
                       float* __restrict__ out) {
    int dn = blockIdx.x, lane = threadIdx.x;   // 64
    int s = offs[dn], e = offs[dn+1], deg = e - s;
    __shared__ float wexp[128];
    __shared__ int ssrc[128];

    if (deg <= 128) {
        float adv = ald[dn];
        for (int j = lane; j < deg; j += 64) {
            int sj = csrc[s + j];
            ssrc[j] = sj;
            float al = als[sj] + adv;
            wexp[j] = (al >= 0.f) ? al : 0.2f*al;
        }
        __syncthreads();
        float m = -1e30f;
        for (int j = lane; j < deg; j += 64) m = fmaxf(m, wexp[j]);
        #pragma unroll
        for (int d = 32; d > 0; d >>= 1) m = fmaxf(m, __shfl_xor(m, d, 64));
        __syncthreads();
        float den = 0.f;
        for (int j = lane; j < deg; j += 64) {
            float ex = __expf(wexp[j] - m);
            wexp[j] = ex;
            den += ex;
        }
        #pragma unroll
        for (int d = 32; d > 0; d >>= 1) den += __shfl_xor(den, d, 64);
        float dinv = 1.f/(den + 1e-16f);
        __syncthreads();
        float2 acc = {0.f, 0.f};
        for (int j = 0; j < deg; j++) {
            float alpha = wexp[j] * dinv;
            float2 v = ((const float2*)(h2 + (size_t)ssrc[j]*C2c))[lane];
            acc.x += alpha*v.x; acc.y += alpha*v.y;
        }
        float2 o;
        o.x = fmaxf(acc.x + b2[2*lane], 0.f);
        o.y = fmaxf(acc.y + b2[2*lane+1], 0.f);
        ((float2*)(out + (size_t)dn*C2c))[lane] = o;
    } else {
        __shared__ float sm[2];
        if (lane == 0) {
            float adv = ald[dn];
            float m = -1e30f;
            for (int j = s; j < e; j++) {
                float al = als[csrc[j]] + adv;
                al = (al >= 0.f) ? al : 0.2f*al;
                m = fmaxf(m, al);
            }
            float den = 0.f;
            for (int j = s; j < e; j++) {
                float al = als[csrc[j]] + adv;
                al = (al >= 0.f) ? al : 0.2f*al;
                den += __expf(al - m);
            }
            sm[0] = m; sm[1] = 1.f/(den + 1e-16f);
        }
        __syncthreads();
        float m = sm[0], dinv = sm[1], adv = ald[dn];
        float2 acc = {0.f, 0.f};
        for (int j = s; j < e; j++) {
            int sj = csrc[j];
            float al = als[sj] + adv;
            al = (al >= 0.f) ? al : 0.2f*al;
            float alpha = __expf(al - m) * dinv;
            float2 v = ((const float2*)(h2 + (size_t)sj*C2c))[lane];
            acc.x += alpha*v.x; acc.y += alpha*v.y;
        }
        float2 o;
        o.x = fmaxf(acc.x + b2[2*lane], 0.f);
        o.y = fmaxf(acc.y + b2[2*lane+1], 0.f);
        ((float2*)(out + (size_t)dn*C2c))[lane] = o;
    }
}

// ---------------- pool + fc_g1 merged (g stays in LDS) ----------------
__global__ void k_poolfcg(const float* __restrict__ hf, const int* __restrict__ batch,
                          const float* __restrict__ W, const float* __restrict__ bias,
                          float* __restrict__ xc) {
    int b = blockIdx.x, tid = threadIdx.x;    // 128
    __shared__ int se[2];
    __shared__ float gs[C2c];
    if (tid < 2) {
        int key = b + tid;
        int lo = 0, hi = N_NODES;
        while (lo < hi) { int mid = (lo+hi) >> 1; if (batch[mid] < key) lo = mid+1; else hi = mid; }
        se[tid] = lo;
    }
    __syncthreads();
    int s = se[0], e = se[1];
    float m = -1e30f;
    for (int n = s; n < e; n++) m = fmaxf(m, hf[(size_t)n*C2c + tid]);
    gs[tid] = m;
    __syncthreads();
    float acc = bias[tid];
    for (int k = 0; k < C2c; k++) acc += gs[k] * W[k*C2c + tid];
    xc[b*256 + tid] = fmaxf(acc, 0.f);
}

// ---------------- conv path ----------------
// buildA streaming rewrite: one block per graph; acc[t][tid] in LDS; stream i in
// natural order (same per-bucket order as sorted version -> bit-identical).
// k_bucket deleted: Amat needs only target[], not ordered/boff.
__global__ void __launch_bounds__(256, 4)
k_buildA(const float* __restrict__ convw, const int* __restrict__ target,
         float* __restrict__ Amat) {
    int b = blockIdx.x;
    int tid = threadIdx.x;                 // 256 = 32 o * 8 k
    int o = tid >> 3, k = tid & 7;
    __shared__ unsigned char tg[SEQc];     // 1 KB
    __shared__ float acc[VOCABc][256];     // 26.6 KB
    for (int i = tid; i < SEQc; i += 256) tg[i] = (unsigned char)target[(size_t)b*SEQc + i];
    #pragma unroll
    for (int t = 0; t < VOCABc; t++) acc[t][tid] = 0.f;
    __syncthreads();
    const float* cw = convw + (size_t)o*SEQc*KWc + k;
    #pragma unroll 4
    for (int i = 0; i < SEQc; i++) {
        int t = tg[i];
        acc[t][tid] += cw[(size_t)i*KWc];
    }
    __syncthreads();
    #pragma unroll
    for (int t = 0; t < VOCABc; t++)
        Amat[(((size_t)b*NFc + o)*VOCABc + t)*KWc + k] = acc[t][tid];
}
__global__ void __launch_bounds__(128, 4)
k_conv(const float* __restrict__ Amat, const float* __restrict__ emb,
       const float* __restrict__ convb, u16* __restrict__ convout) {
    int b = blockIdx.x, og = blockIdx.y;      // og in 0..7 -> o base og*4
    int tid = threadIdx.x;                    // 128
    __shared__ float embs[VOCABc*EMBc];       // 13.3 KB
    __shared__ float arow[4*VOCABc*KWc];      // 3.3 KB
    for (int i = tid; i < VOCABc*EMBc; i += 128) embs[i] = emb[i];
    for (int i = tid; i < 4*VOCABc*KWc; i += 128)
        arow[i] = Amat[((size_t)b*NFc + og*4)*(VOCABc*KWc) + i];
    __syncthreads();
    if (tid < LOUTc) {
        float a0 = convb[og*4+0], a1 = convb[og*4+1], a2 = convb[og*4+2], a3 = convb[og*4+3];
        for (int t = 0; t < VOCABc; t++) {
            #pragma unroll
            for (int k = 0; k < KWc; k++) {
                float ev = embs[t*EMBc + tid + k];
                a0 += arow[0*(VOCABc*KWc) + t*KWc + k] * ev;
                a1 += arow[1*(VOCABc*KWc) + t*KWc + k] * ev;
                a2 += arow[2*(VOCABc*KWc) + t*KWc + k] * ev;
                a3 += arow[3*(VOCABc*KWc) + t*KWc + k] * ev;
            }
        }
        size_t base = (size_t)b*KXT + (og*4)*LOUTc + tid;
        convout[base            ] = f2bf(fmaxf(a0, 0.f));
        convout[base +   LOUTc  ] = f2bf(fmaxf(a1, 0.f));
        convout[base + 2*LOUTc  ] = f2bf(fmaxf(a2, 0.f));
        convout[base + 3*LOUTc  ] = f2bf(fmaxf(a3, 0.f));
    }
}
__global__ void k_fcxt_mfma(const short* __restrict__ cvo, const short* __restrict__ wxt,
                            float* __restrict__ fxp) {
    int wave = threadIdx.x >> 6, lane = threadIdx.x & 63;
    int m16 = lane & 15, quad = lane >> 4;
    int r0 = blockIdx.x*64 + wave*16;      // 512 rows = 8 blocks * 64
    int kt0 = blockIdx.y*11;               // 121 k-steps = 11 chunks * 11
    const short8* arow = (const short8*)(cvo + (size_t)(r0 + m16)*KXT);
    f32x4 acc[8];
    #pragma unroll
    for (int ct = 0; ct < 8; ct++) acc[ct] = (f32x4){0.f,0.f,0.f,0.f};
    for (int kt = kt0; kt < kt0 + 11; kt++) {
        short8 af = arow[kt*4 + quad];
        #pragma unroll
        for (int ct = 0; ct < 8; ct++) {
            const short8* brow = (const short8*)(wxt + (size_t)(ct*16 + m16)*KXT);
            short8 bf = brow[kt*4 + quad];
            acc[ct] = __builtin_amdgcn_mfma_f32_16x16x32_bf16(af, bf, acc[ct], 0, 0, 0);
        }
    }
    #pragma unroll
    for (int ct = 0; ct < 8; ct++) {
        int col = ct*16 + m16;
        #pragma unroll
        for (int r = 0; r < 4; r++) {
            int row = r0 + quad*4 + r;
            fxp[((size_t)blockIdx.y*BGRAPHS + row)*C2c + col] = acc[ct][r];
        }
    }
}

// ---------------- head MLP ----------------
__global__ void k_fc1(const float* __restrict__ xc, const float* __restrict__ fxp,
                      const float* __restrict__ fcxt_b, const float* __restrict__ W,
                      const float* __restrict__ bias, float* __restrict__ y1) {
    int b = blockIdx.x, tid = threadIdx.x;    // 256
    __shared__ float xs[256];
    if (tid < 128) {
        xs[tid] = xc[b*256 + tid];
    } else {
        int col = tid - 128;
        float s = fcxt_b[col];
        #pragma unroll
        for (int q = 0; q < 11; q++) s += fxp[((size_t)q*BGRAPHS + b)*C2c + col];
        xs[tid] = s;
    }
    __syncthreads();
    float a0 = bias[tid], a1 = bias[tid+256], a2 = bias[tid+512], a3 = bias[tid+768];
    for (int k = 0; k < 256; k++) {
        float xk = xs[k];
        const float* wr = W + (size_t)k*1024;
        a0 += xk*wr[tid]; a1 += xk*wr[tid+256]; a2 += xk*wr[tid+512]; a3 += xk*wr[tid+768];
    }
    y1[(size_t)b*1024 + tid      ] = fmaxf(a0, 0.f);
    y1[(size_t)b*1024 + tid + 256] = fmaxf(a1, 0.f);
    y1[(size_t)b*1024 + tid + 512] = fmaxf(a2, 0.f);
    y1[(size_t)b*1024 + tid + 768] = fmaxf(a3, 0.f);
}
__global__ void k_fc2out(const float* __restrict__ y1, const float* __restrict__ W,
                         const float* __restrict__ bias, const float* __restrict__ ow,
                         const float* __restrict__ ob, float* __restrict__ out) {
    int b = blockIdx.x, tid = threadIdx.x;    // 256
    int lane = tid & 63, wid = tid >> 6;
    __shared__ float ys[1024];
    __shared__ float wsum[4];
    for (int i = tid; i < 1024; i += 256) ys[i] = y1[(size_t)b*1024 + i];
    __syncthreads();
    float acc = bias[tid];
    for (int k = 0; k < 1024; k++) acc += ys[k] * W[(size_t)k*256 + tid];
    float v = fmaxf(acc, 0.f) * ow[tid];
    #pragma unroll
    for (int d = 32; d > 0; d >>= 1) v += __shfl_xor(v, d, 64);
    if (lane == 0) wsum[wid] = v;
    __syncthreads();
    if (tid == 0) out[b] = wsum[0] + wsum[1] + wsum[2] + wsum[3] + ob[0];
}

extern "C" void kernel_launch(void* const* d_in, const int* in_sizes, int n_in,
                              void* d_out, int out_size, void* d_ws, size_t ws_size,
                              hipStream_t stream) {
    (void)in_sizes; (void)n_in; (void)out_size;
    if (ws_size < A_END) return;   // guard: clean numeric-fail if ws too small

    const float* x       = (const float*)d_in[0];
    const int*   ei      = (const int*)  d_in[1];
    const int*   batch   = (const int*)  d_in[2];
    const int*   target  = (const int*)  d_in[3];
    const float* W1      = (const float*)d_in[4];
    const float* a_src1  = (const float*)d_in[5];
    const float* a_dst1  = (const float*)d_in[6];
    const float* b1      = (const float*)d_in[7];
    const float* W2      = (const float*)d_in[8];
    const float* a_src2  = (const float*)d_in[9];
    const float* a_dst2  = (const float*)d_in[10];
    const float* b2      = (const float*)d_in[11];
    const float* fcg_w   = (const float*)d_in[12];
    const float* fcg_b   = (const float*)d_in[13];
    const float* emb     = (const float*)d_in[14];
    const float* conv_w  = (const float*)d_in[15];
    const float* conv_b  = (const float*)d_in[16];
    const float* fcxt_w  = (const float*)d_in[17];
    const float* fcxt_b  = (const float*)d_in[18];
    const float* fc1_w   = (const float*)d_in[19];
    const float* fc1_b   = (const float*)d_in[20];
    const float* fc2_w   = (const float*)d_in[21];
    const float* fc2_b   = (const float*)d_in[22];
    const float* out_w   = (const float*)d_in[23];
    const float* out_b   = (const float*)d_in[24];

    char* wsb = (char*)d_ws;
    u16*   xagg  = (u16*)  (wsb + A_HBUF);
    u16*   out1  = (u16*)  (wsb + A_OUT1);
    float* h2    = (float*)(wsb + A_H2);
    __hip_bfloat16* w2t = (__hip_bfloat16*)(wsb + A_W2T);
    float* als1  = (float*)(wsb + A_ALS1);
    float* ald1  = (float*)(wsb + A_ALD1);
    float* als2  = (float*)(wsb + A_ALS2);
    float* ald2  = (float*)(wsb + A_ALD2);
    int*   deg   = (int*)  (wsb + A_DEG);
    int*   offs  = (int*)  (wsb + A_OFFS);
    int*   cur   = (int*)  (wsb + A_CUR);
    int*   csrc  = (int*)  (wsb + A_CSRC);
    float* xc    = (float*)(wsb + A_XC);
    float* y1    = (float*)(wsb + A_Y1);
    float* bpad  = (float*)(wsb + A_BPAD);
    __hip_bfloat16* wxt  = (__hip_bfloat16*)(wsb + A_WXT);
    float* fxp   = (float*)(wsb + A_FXP);
    __hip_bfloat16* w1hp = (__hip_bfloat16*)(wsb + A_W1HP);
    float* wsd   = (float*)(wsb + A_WSD);
    // aliases:
    float* hfin  = (float*)(wsb + A_HFIN);
    float* Amat  = (float*)(wsb + A_AMAT);
    u16*   cvo   = (u16*)  (wsb + A_CVO);
    __hip_bfloat16* xpad = (__hip_bfloat16*)(wsb + A_XPAD);

    // prep
    k_prep<<<(PREP_TOTAL+255)/256, 256, 0, stream>>>(x, W1, W2, b1, fcxt_w, a_src1, a_dst1,
                                                     xpad, w1hp, w2t, bpad, wxt, wsd, deg);
    // CSR build (+ deterministic segment sort)
    k_count  <<<(N_EDGES+255)/256, 256, 0, stream>>>(ei, deg);
    k_scan   <<<1, 1024, 0, stream>>>(deg, offs, cur, N_NODES);
    k_fill   <<<(N_EDGES+N_NODES+255)/256, 256, 0, stream>>>(ei, cur, csrc);
    k_sortcsr<<<(N_NODES+255)/256, 256, 0, stream>>>(offs, csrc);

    // GAT layer 1 in x-space (no h materialization)
    k_att1x<<<(N_NODES*H1c+255)/256, 256, 0, stream>>>(x, wsd, als1, ald1);
    k_agg1x<<<N_NODES, 64, 0, stream>>>((const unsigned*)xpad, als1, ald1, offs, csrc,
                                        (unsigned*)xagg);
    k_gemm1h<<<dim3((N_NODES+63)/64, H1c), 256, 0, stream>>>((const short*)xagg,
                                                             (const short*)w1hp, bpad, out1);
    // ---- xagg dead; xpad dead (out1 region live) ----

    // GAT layer 2 (gemm2 also emits als2/ald2)
    k_gemm2_mfma<<<(N_NODES+63)/64, 256, 0, stream>>>((const short*)out1, (const short*)w2t,
                                                      a_src2, a_dst2, h2, als2, ald2);
    k_agg2<<<N_NODES, 64, 0, stream>>>(h2, als2, ald2, offs, csrc, b2, hfin);

    // pool + fc_g1 -> xc[:, 0:128]
    k_poolfcg<<<BGRAPHS, 128, 0, stream>>>(hfin, batch, fcg_w, fcg_b, xc);

    // conv path -> fxp partials (k_bucket deleted; buildA streams target directly)
    k_buildA<<<BGRAPHS, 256, 0, stream>>>(conv_w, target, Amat);
    k_conv  <<<dim3(BGRAPHS, 8), 128, 0, stream>>>(Amat, emb, conv_b, cvo);
    k_fcxt_mfma<<<dim3(BGRAPHS/64, 11), 256, 0, stream>>>((const short*)cvo, (const short*)wxt, fxp);

    // head MLP
    k_fc1<<<BGRAPHS, 256, 0, stream>>>(xc, fxp, fcxt_b, fc1_w, fc1_b, y1);
    k_fc2out<<<BGRAPHS, 256, 0, stream>>>(y1, fc2_w, fc2_b, out_w, out_b, (float*)d_out);
}

// Round 17
// 655.209 us; speedup vs baseline: 1.0664x; 1.0664x over previous
//
#include <hip/hip_runtime.h>
#include <hip/hip_bf16.h>

// Problem constants (from reference)
#define N_NODES 50000
#define N_EDGES 200000
#define BGRAPHS 512
#define F0c 78
#define H1c 10
#define HC1 780     // H1*F0 (logical)
#define HSTR 800    // padded row stride: 10 head blocks of 80 (78 data + 2 pad)
#define C2c 128
#define SEQc 1000
#define VOCABc 26
#define NFc 32
#define KWc 8
#define LOUTc 121
#define EMBc 128
#define KX 96       // padded cols for xpad (78 -> 96)
#define KXT 3872    // NF*LOUT = 32*121 -> 121 MFMA k-steps, split 11 x 11
#define SELR (BGRAPHS*VOCABc)   // 13312 selector rows
#define SELK 1024               // padded K for buildA gemm (1000 -> 1024)

typedef __attribute__((ext_vector_type(8))) short short8;
typedef __attribute__((ext_vector_type(4))) float f32x4;
typedef unsigned short u16;

static constexpr size_t alignup(size_t x) { return (x + 255) & ~size_t(255); }

// -------- workspace layout (bytes) --------
// A_HBUF region holds xagg bf16 [N][10][80] = 80,000,000 B.
static constexpr size_t A_HBUF = 0;
static constexpr size_t A_OUT1 = alignup(A_HBUF + size_t(N_NODES)*HSTR*2);   // bf16 [N,800] = 80 MB
static constexpr size_t A_H2   = alignup(A_OUT1 + size_t(N_NODES)*HSTR*2);   // f32  [N,128]
static constexpr size_t A_W2T  = alignup(A_H2   + size_t(N_NODES)*C2c*4);    // bf16 [128,800] padded-80 layout
static constexpr size_t A_ALS1 = alignup(A_W2T  + size_t(C2c)*HSTR*2);
static constexpr size_t A_ALD1 = alignup(A_ALS1 + size_t(N_NODES)*H1c*4);
static constexpr size_t A_ALS2 = alignup(A_ALD1 + size_t(N_NODES)*H1c*4);
static constexpr size_t A_ALD2 = alignup(A_ALS2 + size_t(N_NODES)*4);
static constexpr size_t A_DEG  = alignup(A_ALD2 + size_t(N_NODES)*4);
static constexpr size_t A_OFFS = alignup(A_DEG  + size_t(N_NODES)*4);
static constexpr size_t A_CUR  = alignup(A_OFFS + size_t(N_NODES+1)*4);
static constexpr size_t A_CSRC = alignup(A_CUR  + size_t(N_NODES)*4);
static constexpr size_t A_XC   = alignup(A_CSRC + size_t(N_EDGES+N_NODES)*4);
static constexpr size_t A_Y1   = alignup(A_XC   + size_t(BGRAPHS)*256*4);
static constexpr size_t A_BPAD = alignup(A_Y1   + size_t(BGRAPHS)*1024*4);
static constexpr size_t A_WXT  = alignup(A_BPAD + size_t(HSTR)*4);           // bf16 [128][3872]
static constexpr size_t A_FXP  = alignup(A_WXT  + size_t(C2c)*KXT*2);        // f32 [11][512][128]
static constexpr size_t A_W1HP = alignup(A_FXP  + size_t(11)*BGRAPHS*C2c*4); // bf16 [10][80][96]
static constexpr size_t A_WSD  = alignup(A_W1HP + size_t(10)*80*96*2);       // f32 [2][10][78]
static constexpr size_t A_WCVT = alignup(A_WSD  + size_t(2)*H1c*F0c*4);      // bf16 [256][1024]
static constexpr size_t A_END  = alignup(A_WCVT + size_t(256)*SELK*2);

// aliases inside xagg region (valid after k_gemm1h retires; xagg dead then):
static constexpr size_t A_HFIN = A_HBUF;                                        // f32 [N,128]
static constexpr size_t A_AMAT = alignup(A_HFIN + size_t(N_NODES)*C2c*4);       // f32 [512][32][26][8]
static constexpr size_t A_CVO  = alignup(A_AMAT + size_t(BGRAPHS)*NFc*VOCABc*KWc*4);  // bf16 [512][3872]
static constexpr size_t A_SELM = alignup(A_CVO  + size_t(BGRAPHS)*KXT*2);       // bf16 [13312][1024]
static_assert(A_SELM + size_t(SELR)*SELK*2 <= size_t(N_NODES)*HSTR*2, "alias A overflow");
// alias inside out1 region (xpad dead before gemm1h writes out1):
static constexpr size_t A_XPAD = A_OUT1;                                        // bf16 [N,96]
static_assert(size_t(N_NODES)*KX*2 <= size_t(N_NODES)*HSTR*2, "alias B overflow");

// -------- helpers --------
__device__ __forceinline__ float bflo(unsigned u) { return __uint_as_float(u << 16); }
__device__ __forceinline__ float bfhi(unsigned u) { return __uint_as_float(u & 0xffff0000u); }
__device__ __forceinline__ u16 f2bf(float v) {
    __hip_bfloat16 b = __float2bfloat16(v);
    return *(u16*)&b;
}

// ---------------- prep: deg init + conversions + folded attention vectors ----------------
__global__ void k_prep(const float* __restrict__ x, const float* __restrict__ W1,
                       const float* __restrict__ W2, const float* __restrict__ b1,
                       const float* __restrict__ fcxt_w, const float* __restrict__ convw,
                       const float* __restrict__ a_src1, const float* __restrict__ a_dst1,
                       __hip_bfloat16* __restrict__ xpad, __hip_bfloat16* __restrict__ w1hp,
                       __hip_bfloat16* __restrict__ w2t, float* __restrict__ bpad,
                       __hip_bfloat16* __restrict__ wxt, float* __restrict__ wsd,
                       u16* __restrict__ wcvt, int* __restrict__ deg) {
    int i = blockIdx.x*256 + threadIdx.x;
    const int R0 = N_NODES;
    const int R1 = R0 + N_NODES*KX;
    const int R2 = R1 + 10*80*96;
    const int R3 = R2 + C2c*HSTR;
    const int R4 = R3 + HSTR;
    const int R5 = R4 + C2c*KXT;
    const int R6 = R5 + 2*H1c*F0c;
    const int R7 = R6 + 256*SELK;
    if (i < R0) {
        deg[i] = 1;   // self loop
    } else if (i < R1) {
        int t = i - R0; int n = t / KX, c = t - n*KX;
        xpad[t] = __float2bfloat16(c < F0c ? x[(size_t)n*F0c + c] : 0.f);
    } else if (i < R2) {
        int t = i - R1; int hh = t / 7680, rem = t - hh*7680;
        int j = rem / 96, k = rem - j*96;
        w1hp[t] = __float2bfloat16((j < F0c && k < F0c) ? W1[(size_t)k*HC1 + hh*F0c + j] : 0.f);
    } else if (i < R3) {
        int t = i - R2; int c = t / HSTR, p = t - c*HSTR;
        int hh = p / 80, cc = p - hh*80;
        w2t[t] = __float2bfloat16(cc < F0c ? W2[(size_t)(hh*F0c + cc)*C2c + c] : 0.f);
    } else if (i < R4) {
        int p = i - R3; int hh = p / 80, cc = p - hh*80;
        bpad[p] = (cc < F0c) ? b1[hh*F0c + cc] : 0.f;
    } else if (i < R5) {
        int t = i - R4; int c = t / KXT, j = t - c*KXT;
        wxt[t] = __float2bfloat16(fcxt_w[(size_t)j*C2c + c]);
    } else if (i < R6) {
        int t = i - R5; int sd = t / (H1c*F0c), rem = t - sd*(H1c*F0c);
        int hh = rem / F0c, c = rem - hh*F0c;
        const float* a = sd ? a_dst1 : a_src1;
        float v = 0.f;
        for (int j = 0; j < F0c; j++) v += W1[(size_t)c*HC1 + hh*F0c + j] * a[hh*F0c + j];
        wsd[t] = v;
    } else if (i < R7) {
        int t = i - R6; int col = t / SELK, kk = t - col*SELK;
        int o = col >> 3, k = col & 7;
        wcvt[t] = f2bf(kk < SEQc ? convw[((size_t)o*SEQc + kk)*KWc + k] : 0.f);
    }
}
#define PREP_TOTAL (N_NODES + N_NODES*KX + 10*80*96 + C2c*HSTR + HSTR + C2c*KXT + 2*H1c*F0c + 256*SELK)

// ---------------- CSR build ----------------
__global__ void k_count(const int* __restrict__ ei, int* deg) {
    int i = blockIdx.x*256 + threadIdx.x;
    if (i < N_EDGES) atomicAdd(&deg[ei[N_EDGES + i]], 1);
}
__global__ void k_scan(const int* __restrict__ deg, int* __restrict__ off,
                       int* __restrict__ cur, int n) {
    __shared__ int wsum[16];
    __shared__ int s_carry;
    int tid = threadIdx.x, lane = tid & 63, wid = tid >> 6;
    if (tid == 0) s_carry = 0;
    __syncthreads();
    for (int base = 0; base < n; base += 1024) {
        int i = base + tid;
        int v0 = (i < n) ? deg[i] : 0;
        int v = v0;
        for (int d = 1; d < 64; d <<= 1) { int t = __shfl_up(v, d, 64); if (lane >= d) v += t; }
        if (lane == 63) wsum[wid] = v;
        __syncthreads();
        if (wid == 0) {
            int w = (lane < 16) ? wsum[lane] : 0;
            for (int d = 1; d < 16; d <<= 1) { int t = __shfl_up(w, d, 64); if (lane >= d) w += t; }
            if (lane < 16) wsum[lane] = w;
        }
        __syncthreads();
        int wprev = (wid > 0) ? wsum[wid-1] : 0;
        int carry = s_carry;
        if (i < n) { int o = carry + wprev + (v - v0); off[i] = o; cur[i] = o; }
        __syncthreads();
        if (tid == 0) s_carry = carry + wsum[15];
        __syncthreads();
    }
    if (tid == 0) off[n] = s_carry;
}
__global__ void k_fill(const int* __restrict__ ei, int* cur, int* __restrict__ csrc) {
    int i = blockIdx.x*256 + threadIdx.x;
    if (i < N_EDGES) {
        int s = ei[i], d = ei[N_EDGES + i];
        int p = atomicAdd(&cur[d], 1);
        csrc[p] = s;
    } else if (i < N_EDGES + N_NODES) {
        int n = i - N_EDGES;
        int p = atomicAdd(&cur[n], 1);
        csrc[p] = n;
    }
}
// determinize: sort each CSR segment (atomic fill order varies run-to-run)
__global__ void k_sortcsr(const int* __restrict__ offs, int* __restrict__ csrc) {
    int n = blockIdx.x*256 + threadIdx.x;
    if (n >= N_NODES) return;
    int s = offs[n], e = offs[n+1];
    for (int i = s + 1; i < e; i++) {
        int v = csrc[i];
        int j = i - 1;
        while (j >= s && csrc[j] > v) { csrc[j+1] = csrc[j]; j--; }
        csrc[j+1] = v;
    }
}

// ---------------- layer-1 attention logits, direct from x: als = x @ (W1_h a_h) ----------------
__global__ void k_att1x(const float* __restrict__ x, const float* __restrict__ wsd,
                        float* __restrict__ als, float* __restrict__ ald) {
    int i = blockIdx.x*256 + threadIdx.x;
    if (i >= N_NODES*H1c) return;
    int n = i / H1c, hh = i - n*H1c;
    const float* xr = x + (size_t)n*F0c;
    const float* ws = wsd + hh*F0c;
    const float* wd = wsd + H1c*F0c + hh*F0c;
    float s1 = 0.f, s2 = 0.f;
    for (int c = 0; c < F0c; c++) { float v = xr[c]; s1 += v*ws[c]; s2 += v*wd[c]; }
    als[i] = s1; ald[i] = s2;
}

// ---------------- layer-1 aggregation in x-space: xagg[n,hh,80] = sum alpha * x[src] ----------------
__global__ void k_agg1x(const unsigned* __restrict__ xpu, const float* __restrict__ als,
                        const float* __restrict__ ald, const int* __restrict__ offs,
                        const int* __restrict__ csrc, unsigned* __restrict__ xaggu) {
    constexpr int H = H1c;
    int dn = blockIdx.x, lane = threadIdx.x;   // 64
    int s = offs[dn], e = offs[dn+1], deg = e - s;
    __shared__ float wexp[64*H];               // 2560 B
    __shared__ int   ssrc[64];
    __shared__ float ms[H], dinv_s[H];

    if (deg <= 64) {
        if (lane < deg) ssrc[lane] = csrc[s + lane];
        __syncthreads();
        for (int idx = lane; idx < deg*H; idx += 64) {
            int j = idx / H, hh = idx - j*H;
            float al = als[(size_t)ssrc[j]*H + hh] + ald[(size_t)dn*H + hh];
            wexp[idx] = (al >= 0.f) ? al : 0.2f*al;
        }
        __syncthreads();
        if (lane < H) {
            float m = -1e30f;
            for (int j = 0; j < deg; j++) m = fmaxf(m, wexp[j*H + lane]);
            float den = 0.f;
            for (int j = 0; j < deg; j++) den += __expf(wexp[j*H + lane] - m);
            ms[lane] = m; dinv_s[lane] = 1.f/(den + 1e-16f);
        }
        __syncthreads();
        for (int idx = lane; idx < deg*H; idx += 64) {
            int hh = idx % H;
            wexp[idx] = __expf(wexp[idx] - ms[hh]) * dinv_s[hh];
        }
        __syncthreads();
        if (lane < 40) {                       // uint c covers x cols 2c,2c+1 (cols 0..79)
            float accL[H], accH[H];
            #pragma unroll
            for (int hh = 0; hh < H; hh++) { accL[hh] = 0.f; accH[hh] = 0.f; }
            int j = 0;
            for (; j + 1 < deg; j += 2) {
                unsigned ua = xpu[(size_t)ssrc[j]*48 + lane];
                unsigned ub = xpu[(size_t)ssrc[j+1]*48 + lane];
                float a0 = bflo(ua), a1 = bfhi(ua), b0 = bflo(ub), b1 = bfhi(ub);
                #pragma unroll
                for (int hh = 0; hh < H; hh++) {
                    float wA = wexp[j*H + hh], wB = wexp[(j+1)*H + hh];
                    accL[hh] += wA*a0 + wB*b0;
                    accH[hh] += wA*a1 + wB*b1;
                }
            }
            if (j < deg) {
                unsigned ua = xpu[(size_t)ssrc[j]*48 + lane];
                float a0 = bflo(ua), a1 = bfhi(ua);
                #pragma unroll
                for (int hh = 0; hh < H; hh++) {
                    float wA = wexp[j*H + hh];
                    accL[hh] += wA*a0;
                    accH[hh] += wA*a1;
                }
            }
            #pragma unroll
            for (int hh = 0; hh < H; hh++) {
                unsigned p = (unsigned)f2bf(accL[hh]) | ((unsigned)f2bf(accH[hh]) << 16);
                xaggu[((size_t)dn*H + hh)*40 + lane] = p;
            }
        }
    } else {
        // fallback deg>64 (practically never): recompute alpha inline, guaranteed correct
        if (lane < H) {
            float adv = ald[(size_t)dn*H + lane];
            float m = -1e30f;
            for (int j = s; j < e; j++) {
                float al = als[(size_t)csrc[j]*H + lane] + adv;
                al = (al >= 0.f) ? al : 0.2f*al;
                m = fmaxf(m, al);
            }
            float den = 0.f;
            for (int j = s; j < e; j++) {
                float al = als[(size_t)csrc[j]*H + lane] + adv;
                al = (al >= 0.f) ? al : 0.2f*al;
                den += __expf(al - m);
            }
            ms[lane] = m; dinv_s[lane] = 1.f/(den + 1e-16f);
        }
        __syncthreads();
        if (lane < 40) {
            float accL[H], accH[H];
            #pragma unroll
            for (int hh = 0; hh < H; hh++) { accL[hh] = 0.f; accH[hh] = 0.f; }
            for (int j = s; j < e; j++) {
                int sj = csrc[j];
                unsigned ua = xpu[(size_t)sj*48 + lane];
                float a0 = bflo(ua), a1 = bfhi(ua);
                #pragma unroll
                for (int hh = 0; hh < H; hh++) {
                    float al = als[(size_t)sj*H + hh] + ald[(size_t)dn*H + hh];
                    al = (al >= 0.f) ? al : 0.2f*al;
                    float a = __expf(al - ms[hh]) * dinv_s[hh];
                    accL[hh] += a*a0;
                    accH[hh] += a*a1;
                }
            }
            #pragma unroll
            for (int hh = 0; hh < H; hh++) {
                unsigned p = (unsigned)f2bf(accL[hh]) | ((unsigned)f2bf(accH[hh]) << 16);
                xaggu[((size_t)dn*H + hh)*40 + lane] = p;
            }
        }
    }
}

// ---------------- per-head GEMM: xagg[n,hh,80] @ W1_hh[80x80] -> out1 (elu+bias fused) ----------------
__global__ void k_gemm1h(const short* __restrict__ xagg, const short* __restrict__ w1hp,
                         const float* __restrict__ bpad, u16* __restrict__ out1) {
    int wave = threadIdx.x >> 6, lane = threadIdx.x & 63;
    int m16 = lane & 15, quad = lane >> 4;
    int hh = blockIdx.y;
    int r0 = blockIdx.x*64 + wave*16;
    int rowc = min(r0 + m16, N_NODES-1);
    const short8* arow = (const short8*)(xagg + ((size_t)rowc*H1c + hh)*80);
    f32x4 acc[5];
    #pragma unroll
    for (int ct = 0; ct < 5; ct++) acc[ct] = (f32x4){0.f,0.f,0.f,0.f};
    #pragma unroll
    for (int kt = 0; kt < 3; kt++) {
        short8 af = arow[kt*4 + quad];    // kt=2,quad>=2 overreads: B zeros neutralize
        #pragma unroll
        for (int ct = 0; ct < 5; ct++) {
            const short8* brow = (const short8*)(w1hp + (size_t)(hh*80 + ct*16 + m16)*96);
            short8 bf = brow[kt*4 + quad];
            acc[ct] = __builtin_amdgcn_mfma_f32_16x16x32_bf16(af, bf, acc[ct], 0, 0, 0);
        }
    }
    #pragma unroll
    for (int ct = 0; ct < 5; ct++) {
        int col = ct*16 + m16;
        float bv = bpad[hh*80 + col];
        #pragma unroll
        for (int r = 0; r < 4; r++) {
            int orow = r0 + quad*4 + r;
            if (orow < N_NODES) {
                float v = acc[ct][r] + bv;
                v = (v > 0.f) ? v : (__expf(v) - 1.f);
                out1[(size_t)orow*HSTR + hh*80 + col] = f2bf(v);
            }
        }
    }
}

// ---------------- GEMM2 (MFMA) + att2 fold: out1 @ W2t^T -> h2, als2, ald2 ----------------
__global__ void k_gemm2_mfma(const short* __restrict__ A, const short* __restrict__ Bt,
                             const float* __restrict__ a_src2, const float* __restrict__ a_dst2,
                             float* __restrict__ Cout, float* __restrict__ als2,
                             float* __restrict__ ald2) {
    int wave = threadIdx.x >> 6, lane = threadIdx.x & 63;
    int m16 = lane & 15, quad = lane >> 4;
    int r0 = blockIdx.x*64 + wave*16;
    int rowc = min(r0 + m16, N_NODES-1);
    const short8* arow = (const short8*)(A + (size_t)rowc*HSTR);
    f32x4 acc[8];
    #pragma unroll
    for (int ct = 0; ct < 8; ct++) acc[ct] = (f32x4){0.f,0.f,0.f,0.f};
    for (int kt = 0; kt < 25; kt++) {
        short8 af = arow[kt*4 + quad];
        #pragma unroll
        for (int ct = 0; ct < 8; ct++) {
            const short8* brow = (const short8*)(Bt + (size_t)(ct*16 + m16)*HSTR);
            short8 bf = brow[kt*4 + quad];
            acc[ct] = __builtin_amdgcn_mfma_f32_16x16x32_bf16(af, bf, acc[ct], 0, 0, 0);
        }
    }
    #pragma unroll
    for (int ct = 0; ct < 8; ct++) {
        #pragma unroll
        for (int r = 0; r < 4; r++) {
            int orow = r0 + quad*4 + r;
            if (orow < N_NODES) Cout[(size_t)orow*C2c + ct*16 + m16] = acc[ct][r];
        }
    }
    float asv[8], adv[8];
    #pragma unroll
    for (int ct = 0; ct < 8; ct++) { asv[ct] = a_src2[ct*16 + m16]; adv[ct] = a_dst2[ct*16 + m16]; }
    #pragma unroll
    for (int r = 0; r < 4; r++) {
        float s1 = 0.f, s2 = 0.f;
        #pragma unroll
        for (int ct = 0; ct < 8; ct++) { s1 += acc[ct][r]*asv[ct]; s2 += acc[ct][r]*adv[ct]; }
        #pragma unroll
        for (int d = 1; d < 16; d <<= 1) { s1 += __shfl_xor(s1, d, 64); s2 += __shfl_xor(s2, d, 64); }
        int orow = r0 + quad*4 + r;
        if (m16 == 0 && orow < N_NODES) { als2[orow] = s1; ald2[orow] = s2; }
    }
}

// ---------------- GAT layer-2 aggregation (H=1, C=128 f32) ----------------
__global__ void k_agg2(const float* __restrict__ h2, const float* __restrict__ als,
                       const float* __restrict__ ald, const int* __restrict__ offs,
                       const int* __restrict__ csrc, const float* __restrict__ b2,
                       float* __restrict__ out) {
    int dn = blockIdx.x, lane = threadIdx.x;   // 64
    int s = offs[dn], e = offs[dn+1], deg = e - s;
    __shared__ float wexp[128];
    __shared__ int ssrc[128];

    if (deg <= 128) {
        float adv = ald[dn];
        for (int j = lane; j < deg; j += 64) {
            int sj = csrc[s + j];
            ssrc[j] = sj;
            float al = als[sj] + adv;
            wexp[j] = (al >= 0.f) ? al : 0.2f*al;
        }
        __syncthreads();
        float m = -1e30f;
        for (int j = lane; j < deg; j += 64) m = fmaxf(m, wexp[j]);
        #pragma unroll
        for (int d = 32; d > 0; d >>= 1) m = fmaxf(m, __shfl_xor(m, d, 64));
        __syncthreads();
        float den = 0.f;
        for (int j = lane; j < deg; j += 64) {
            float ex = __expf(wexp[j] - m);
            wexp[j] = ex;
            den += ex;
        }
        #pragma unroll
        for (int d = 32; d > 0; d >>= 1) den += __shfl_xor(den, d, 64);
        float dinv = 1.f/(den + 1e-16f);
        __syncthreads();
        float2 acc = {0.f, 0.f};
        for (int j = 0; j < deg; j++) {
            float alpha = wexp[j] * dinv;
            float2 v = ((const float2*)(h2 + (size_t)ssrc[j]*C2c))[lane];
            acc.x += alpha*v.x; acc.y += alpha*v.y;
        }
        float2 o;
        o.x = fmaxf(acc.x + b2[2*lane], 0.f);
        o.y = fmaxf(acc.y + b2[2*lane+1], 0.f);
        ((float2*)(out + (size_t)dn*C2c))[lane] = o;
    } else {
        __shared__ float sm[2];
        if (lane == 0) {
            float adv = ald[dn];
            float m = -1e30f;
            for (int j = s; j < e; j++) {
                float al = als[csrc[j]] + adv;
                al = (al >= 0.f) ? al : 0.2f*al;
                m = fmaxf(m, al);
            }
            float den = 0.f;
            for (int j = s; j < e; j++) {
                float al = als[csrc[j]] + adv;
                al = (al >= 0.f) ? al : 0.2f*al;
                den += __expf(al - m);
            }
            sm[0] = m; sm[1] = 1.f/(den + 1e-16f);
        }
        __syncthreads();
        float m = sm[0], dinv = sm[1], adv = ald[dn];
        float2 acc = {0.f, 0.f};
        for (int j = s; j < e; j++) {
            int sj = csrc[j];
            float al = als[sj] + adv;
            al = (al >= 0.f) ? al : 0.2f*al;
            float alpha = __expf(al - m) * dinv;
            float2 v = ((const float2*)(h2 + (size_t)sj*C2c))[lane];
            acc.x += alpha*v.x; acc.y += alpha*v.y;
        }
        float2 o;
        o.x = fmaxf(acc.x + b2[2*lane], 0.f);
        o.y = fmaxf(acc.y + b2[2*lane+1], 0.f);
        ((float2*)(out + (size_t)dn*C2c))[lane] = o;
    }
}

// ---------------- pool + fc_g1 merged (g stays in LDS) ----------------
__global__ void k_poolfcg(const float* __restrict__ hf, const int* __restrict__ batch,
                          const float* __restrict__ W, const float* __restrict__ bias,
                          float* __restrict__ xc) {
    int b = blockIdx.x, tid = threadIdx.x;    // 128
    __shared__ int se[2];
    __shared__ float gs[C2c];
    if (tid < 2) {
        int key = b + tid;
        int lo = 0, hi = N_NODES;
        while (lo < hi) { int mid = (lo+hi) >> 1; if (batch[mid] < key) lo = mid+1; else hi = mid; }
        se[tid] = lo;
    }
    __syncthreads();
    int s = se[0], e = se[1];
    float m = -1e30f;
    for (int n = s; n < e; n++) m = fmaxf(m, hf[(size_t)n*C2c + tid]);
    gs[tid] = m;
    __syncthreads();
    float acc = bias[tid];
    for (int k = 0; k < C2c; k++) acc += gs[k] * W[k*C2c + tid];
    xc[b*256 + tid] = fmaxf(acc, 0.f);
}

// ---------------- conv path ----------------
// selector matrix M[(b*26+t)][i] = (target[b,i]==t) in bf16; disjoint writes, deterministic
__global__ void k_selmat(const int* __restrict__ target, u16* __restrict__ selm) {
    int b = blockIdx.x, tid = threadIdx.x;    // 256
    size_t base = (size_t)b*VOCABc*SELK;
    for (int i = tid; i < VOCABc*SELK; i += 256) selm[base + i] = 0;
    __syncthreads();
    for (int i = tid; i < SEQc; i += 256) {
        int t = target[(size_t)b*SEQc + i];
        selm[base + (size_t)t*SELK + i] = 0x3F80;   // bf16(1.0)
    }
}
// buildA as MFMA GEMM: selm[13312,1024] @ wcvt[256,1024]^T -> Amat (scattered epilogue)
__global__ void k_buildA_mfma(const short* __restrict__ selm, const short* __restrict__ wcvt,
                              float* __restrict__ Amat) {
    int wave = threadIdx.x >> 6, lane = threadIdx.x & 63;
    int m16 = lane & 15, quad = lane >> 4;
    int r0 = blockIdx.x*64 + wave*16;      // 13312 rows = 208 blocks * 64
    int c0 = blockIdx.y*128;               // 256 cols = 2 * 128
    const short8* arow = (const short8*)(selm + (size_t)(r0 + m16)*SELK);
    f32x4 acc[8];
    #pragma unroll
    for (int ct = 0; ct < 8; ct++) acc[ct] = (f32x4){0.f,0.f,0.f,0.f};
    for (int kt = 0; kt < SELK/32; kt++) {   // 32 k-steps
        short8 af = arow[kt*4 + quad];
        #pragma unroll
        for (int ct = 0; ct < 8; ct++) {
            const short8* brow = (const short8*)(wcvt + (size_t)(c0 + ct*16 + m16)*SELK);
            short8 bf = brow[kt*4 + quad];
            acc[ct] = __builtin_amdgcn_mfma_f32_16x16x32_bf16(af, bf, acc[ct], 0, 0, 0);
        }
    }
    #pragma unroll
    for (int ct = 0; ct < 8; ct++) {
        int col = c0 + ct*16 + m16;        // (o,k): o=col>>3, k=col&7
        int o = col >> 3, k = col & 7;
        #pragma unroll
        for (int r = 0; r < 4; r++) {
            int row = r0 + quad*4 + r;     // (b,t): b=row/26, t=row%26
            int b = row / VOCABc, t = row - b*VOCABc;
            Amat[(((size_t)b*NFc + o)*VOCABc + t)*KWc + k] = acc[ct][r];
        }
    }
}
__global__ void __launch_bounds__(128, 4)
k_conv(const float* __restrict__ Amat, const float* __restrict__ emb,
       const float* __restrict__ convb, u16* __restrict__ convout) {
    int b = blockIdx.x, og = blockIdx.y;      // og in 0..7 -> o base og*4
    int tid = threadIdx.x;                    // 128
    __shared__ float embs[VOCABc*EMBc];       // 13.3 KB
    __shared__ float arow[4*VOCABc*KWc];      // 3.3 KB
    for (int i = tid; i < VOCABc*EMBc; i += 128) embs[i] = emb[i];
    for (int i = tid; i < 4*VOCABc*KWc; i += 128)
        arow[i] = Amat[((size_t)b*NFc + og*4)*(VOCABc*KWc) + i];
    __syncthreads();
    if (tid < LOUTc) {
        float a0 = convb[og*4+0], a1 = convb[og*4+1], a2 = convb[og*4+2], a3 = convb[og*4+3];
        for (int t = 0; t < VOCABc; t++) {
            #pragma unroll
            for (int k = 0; k < KWc; k++) {
                float ev = embs[t*EMBc + tid + k];
                a0 += arow[0*(VOCABc*KWc) + t*KWc + k] * ev;
                a1 += arow[1*(VOCABc*KWc) + t*KWc + k] * ev;
                a2 += arow[2*(VOCABc*KWc) + t*KWc + k] * ev;
                a3 += arow[3*(VOCABc*KWc) + t*KWc + k] * ev;
            }
        }
        size_t base = (size_t)b*KXT + (og*4)*LOUTc + tid;
        convout[base            ] = f2bf(fmaxf(a0, 0.f));
        convout[base +   LOUTc  ] = f2bf(fmaxf(a1, 0.f));
        convout[base + 2*LOUTc  ] = f2bf(fmaxf(a2, 0.f));
        convout[base + 3*LOUTc  ] = f2bf(fmaxf(a3, 0.f));
    }
}
__global__ void k_fcxt_mfma(const short* __restrict__ cvo, const short* __restrict__ wxt,
                            float* __restrict__ fxp) {
    int wave = threadIdx.x >> 6, lane = threadIdx.x & 63;
    int m16 = lane & 15, quad = lane >> 4;
    int r0 = blockIdx.x*64 + wave*16;      // 512 rows = 8 blocks * 64
    int kt0 = blockIdx.y*11;               // 121 k-steps = 11 chunks * 11
    const short8* arow = (const short8*)(cvo + (size_t)(r0 + m16)*KXT);
    f32x4 acc[8];
    #pragma unroll
    for (int ct = 0; ct < 8; ct++) acc[ct] = (f32x4){0.f,0.f,0.f,0.f};
    for (int kt = kt0; kt < kt0 + 11; kt++) {
        short8 af = arow[kt*4 + quad];
        #pragma unroll
        for (int ct = 0; ct < 8; ct++) {
            const short8* brow = (const short8*)(wxt + (size_t)(ct*16 + m16)*KXT);
            short8 bf = brow[kt*4 + quad];
            acc[ct] = __builtin_amdgcn_mfma_f32_16x16x32_bf16(af, bf, acc[ct], 0, 0, 0);
        }
    }
    #pragma unroll
    for (int ct = 0; ct < 8; ct++) {
        int col = ct*16 + m16;
        #pragma unroll
        for (int r = 0; r < 4; r++) {
            int row = r0 + quad*4 + r;
            fxp[((size_t)blockIdx.y*BGRAPHS + row)*C2c + col] = acc[ct][r];
        }
    }
}

// ---------------- head MLP ----------------
__global__ void k_fc1(const float* __restrict__ xc, const float* __restrict__ fxp,
                      const float* __restrict__ fcxt_b, const float* __restrict__ W,
                      const float* __restrict__ bias, float* __restrict__ y1) {
    int b = blockIdx.x, tid = threadIdx.x;    // 256
    __shared__ float xs[256];
    if (tid < 128) {
        xs[tid] = xc[b*256 + tid];
    } else {
        int col = tid - 128;
        float s = fcxt_b[col];
        #pragma unroll
        for (int q = 0; q < 11; q++) s += fxp[((size_t)q*BGRAPHS + b)*C2c + col];
        xs[tid] = s;
    }
    __syncthreads();
    float a0 = bias[tid], a1 = bias[tid+256], a2 = bias[tid+512], a3 = bias[tid+768];
    for (int k = 0; k < 256; k++) {
        float xk = xs[k];
        const float* wr = W + (size_t)k*1024;
        a0 += xk*wr[tid]; a1 += xk*wr[tid+256]; a2 += xk*wr[tid+512]; a3 += xk*wr[tid+768];
    }
    y1[(size_t)b*1024 + tid      ] = fmaxf(a0, 0.f);
    y1[(size_t)b*1024 + tid + 256] = fmaxf(a1, 0.f);
    y1[(size_t)b*1024 + tid + 512] = fmaxf(a2, 0.f);
    y1[(size_t)b*1024 + tid + 768] = fmaxf(a3, 0.f);
}
__global__ void k_fc2out(const float* __restrict__ y1, const float* __restrict__ W,
                         const float* __restrict__ bias, const float* __restrict__ ow,
                         const float* __restrict__ ob, float* __restrict__ out) {
    int b = blockIdx.x, tid = threadIdx.x;    // 256
    int lane = tid & 63, wid = tid >> 6;
    __shared__ float ys[1024];
    __shared__ float wsum[4];
    for (int i = tid; i < 1024; i += 256) ys[i] = y1[(size_t)b*1024 + i];
    __syncthreads();
    float acc = bias[tid];
    for (int k = 0; k < 1024; k++) acc += ys[k] * W[(size_t)k*256 + tid];
    float v = fmaxf(acc, 0.f) * ow[tid];
    #pragma unroll
    for (int d = 32; d > 0; d >>= 1) v += __shfl_xor(v, d, 64);
    if (lane == 0) wsum[wid] = v;
    __syncthreads();
    if (tid == 0) out[b] = wsum[0] + wsum[1] + wsum[2] + wsum[3] + ob[0];
}

extern "C" void kernel_launch(void* const* d_in, const int* in_sizes, int n_in,
                              void* d_out, int out_size, void* d_ws, size_t ws_size,
                              hipStream_t stream) {
    (void)in_sizes; (void)n_in; (void)out_size;
    if (ws_size < A_END) return;   // guard: clean numeric-fail if ws too small

    const float* x       = (const float*)d_in[0];
    const int*   ei      = (const int*)  d_in[1];
    const int*   batch   = (const int*)  d_in[2];
    const int*   target  = (const int*)  d_in[3];
    const float* W1      = (const float*)d_in[4];
    const float* a_src1  = (const float*)d_in[5];
    const float* a_dst1  = (const float*)d_in[6];
    const float* b1      = (const float*)d_in[7];
    const float* W2      = (const float*)d_in[8];
    const float* a_src2  = (const float*)d_in[9];
    const float* a_dst2  = (const float*)d_in[10];
    const float* b2      = (const float*)d_in[11];
    const float* fcg_w   = (const float*)d_in[12];
    const float* fcg_b   = (const float*)d_in[13];
    const float* emb     = (const float*)d_in[14];
    const float* conv_w  = (const float*)d_in[15];
    const float* conv_b  = (const float*)d_in[16];
    const float* fcxt_w  = (const float*)d_in[17];
    const float* fcxt_b  = (const float*)d_in[18];
    const float* fc1_w   = (const float*)d_in[19];
    const float* fc1_b   = (const float*)d_in[20];
    const float* fc2_w   = (const float*)d_in[21];
    const float* fc2_b   = (const float*)d_in[22];
    const float* out_w   = (const float*)d_in[23];
    const float* out_b   = (const float*)d_in[24];

    char* wsb = (char*)d_ws;
    u16*   xagg  = (u16*)  (wsb + A_HBUF);
    u16*   out1  = (u16*)  (wsb + A_OUT1);
    float* h2    = (float*)(wsb + A_H2);
    __hip_bfloat16* w2t = (__hip_bfloat16*)(wsb + A_W2T);
    float* als1  = (float*)(wsb + A_ALS1);
    float* ald1  = (float*)(wsb + A_ALD1);
    float* als2  = (float*)(wsb + A_ALS2);
    float* ald2  = (float*)(wsb + A_ALD2);
    int*   deg   = (int*)  (wsb + A_DEG);
    int*   offs  = (int*)  (wsb + A_OFFS);
    int*   cur   = (int*)  (wsb + A_CUR);
    int*   csrc  = (int*)  (wsb + A_CSRC);
    float* xc    = (float*)(wsb + A_XC);
    float* y1    = (float*)(wsb + A_Y1);
    float* bpad  = (float*)(wsb + A_BPAD);
    __hip_bfloat16* wxt  = (__hip_bfloat16*)(wsb + A_WXT);
    float* fxp   = (float*)(wsb + A_FXP);
    __hip_bfloat16* w1hp = (__hip_bfloat16*)(wsb + A_W1HP);
    float* wsd   = (float*)(wsb + A_WSD);
    u16*   wcvt  = (u16*)  (wsb + A_WCVT);
    // aliases:
    float* hfin  = (float*)(wsb + A_HFIN);
    float* Amat  = (float*)(wsb + A_AMAT);
    u16*   cvo   = (u16*)  (wsb + A_CVO);
    u16*   selm  = (u16*)  (wsb + A_SELM);
    __hip_bfloat16* xpad = (__hip_bfloat16*)(wsb + A_XPAD);

    // prep
    k_prep<<<(PREP_TOTAL+255)/256, 256, 0, stream>>>(x, W1, W2, b1, fcxt_w, conv_w,
                                                     a_src1, a_dst1,
                                                     xpad, w1hp, w2t, bpad, wxt, wsd,
                                                     wcvt, deg);
    // CSR build (+ deterministic segment sort)
    k_count  <<<(N_EDGES+255)/256, 256, 0, stream>>>(ei, deg);
    k_scan   <<<1, 1024, 0, stream>>>(deg, offs, cur, N_NODES);
    k_fill   <<<(N_EDGES+N_NODES+255)/256, 256, 0, stream>>>(ei, cur, csrc);
    k_sortcsr<<<(N_NODES+255)/256, 256, 0, stream>>>(offs, csrc);

    // GAT layer 1 in x-space (no h materialization)
    k_att1x<<<(N_NODES*H1c+255)/256, 256, 0, stream>>>(x, wsd, als1, ald1);
    k_agg1x<<<N_NODES, 64, 0, stream>>>((const unsigned*)xpad, als1, ald1, offs, csrc,
                                        (unsigned*)xagg);
    k_gemm1h<<<dim3((N_NODES+63)/64, H1c), 256, 0, stream>>>((const short*)xagg,
                                                             (const short*)w1hp, bpad, out1);
    // ---- xagg dead; xpad dead (out1 region live) ----

    // GAT layer 2 (gemm2 also emits als2/ald2)
    k_gemm2_mfma<<<(N_NODES+63)/64, 256, 0, stream>>>((const short*)out1, (const short*)w2t,
                                                      a_src2, a_dst2, h2, als2, ald2);
    k_agg2<<<N_NODES, 64, 0, stream>>>(h2, als2, ald2, offs, csrc, b2, hfin);

    // pool + fc_g1 -> xc[:, 0:128]
    k_poolfcg<<<BGRAPHS, 128, 0, stream>>>(hfin, batch, fcg_w, fcg_b, xc);

    // conv path -> fxp partials (buildA as selector-GEMM)
    k_selmat<<<BGRAPHS, 256, 0, stream>>>(target, selm);
    k_buildA_mfma<<<dim3(SELR/64, 2), 256, 0, stream>>>((const short*)selm, (const short*)wcvt, Amat);
    k_conv  <<<dim3(BGRAPHS, 8), 128, 0, stream>>>(Amat, emb, conv_b, cvo);
    k_fcxt_mfma<<<dim3(BGRAPHS/64, 11), 256, 0, stream>>>((const short*)cvo, (const short*)wxt, fxp);

    // head MLP
    k_fc1<<<BGRAPHS, 256, 0, stream>>>(xc, fxp, fcxt_b, fc1_w, fc1_b, y1);
    k_fc2out<<<BGRAPHS, 256, 0, stream>>>(y1, fc2_w, fc2_b, out_w, out_b, (float*)d_out);
}